// Round 2
// baseline (157.722 us; speedup 1.0000x reference)
//
#include <hip/hip_runtime.h>
#include <math.h>

#define NQ 4
#define DIM 16
#define BB 4
#define SS 512
#define EE 512
#define ROWS (BB * SS)   // 2048

// ---------------------------------------------------------------------------
// Kernel 1: build circuit unitary U (16x16 complex), reduce to real symmetric
// Mr (score = amp^T Mr amp for real encoded amp), then compress to the 81
// trigonometric-polynomial coefficients T[e0][e1][e2][e3] (e in {1,cos,sin})
// such that  score/sqrt(4) = sum_e T[e] * prod_w basis_{e_w}(t_w).
// Stored padded as [27][4] float (pad = 0) for ds_read_b128 in k_attn.
// ---------------------------------------------------------------------------
__global__ void k_circuit(const float* __restrict__ qw, float* __restrict__ T_out) {
    __shared__ float Ur[DIM][DIM];  // [idx][col]
    __shared__ float Ui[DIM][DIM];
    __shared__ float sMr[256];
    int t = threadIdx.x;
    if (t < DIM) {
        float vr[DIM], vi[DIM];
#pragma unroll
        for (int i = 0; i < DIM; ++i) { vr[i] = (i == t) ? 1.f : 0.f; vi[i] = 0.f; }
#pragma unroll
        for (int layer = 0; layer < 2; ++layer) {
#pragma unroll
            for (int w = 0; w < NQ; ++w) {
                float a = qw[(layer * NQ + w) * 3 + 0] * 0.5f;
                float b = qw[(layer * NQ + w) * 3 + 1] * 0.5f;
                float c = qw[(layer * NQ + w) * 3 + 2] * 0.5f;
                float sa, ca, sb, cb, sc, cc;
                sincosf(a, &sa, &ca);
                sincosf(b, &sb, &cb);
                sincosf(c, &sc, &cc);
                float m00r = cb * ca, m00i = sb * sa;
                float m01r = -sb * ca, m01i = -cb * sa;
                float m10r = sb * ca, m10i = -cb * sa;
                float m11r = cb * ca, m11i = -sb * sa;
                float g00r = cc * m00r + sc * m00i, g00i = cc * m00i - sc * m00r;
                float g01r = cc * m01r + sc * m01i, g01i = cc * m01i - sc * m01r;
                float g10r = cc * m10r - sc * m10i, g10i = cc * m10i + sc * m10r;
                float g11r = cc * m11r - sc * m11i, g11i = cc * m11i + sc * m11r;
                int mask = 1 << (3 - w);
#pragma unroll
                for (int idx = 0; idx < DIM; ++idx) {
                    if (idx & mask) continue;
                    int i1 = idx | mask;
                    float r0 = vr[idx], i0 = vi[idx], r1 = vr[i1], i1v = vi[i1];
                    vr[idx] = g00r * r0 - g00i * i0 + g01r * r1 - g01i * i1v;
                    vi[idx] = g00r * i0 + g00i * r0 + g01r * i1v + g01i * r1;
                    vr[i1]  = g10r * r0 - g10i * i0 + g11r * r1 - g11i * i1v;
                    vi[i1]  = g10r * i0 + g10i * r0 + g11r * i1v + g11i * r1;
                }
            }
            const int cwire[4] = {0, 1, 2, 3};
            const int twire[4] = {1, 2, 3, 0};
#pragma unroll
            for (int e = 0; e < 4; ++e) {
                int cmask = 1 << (3 - cwire[e]);
                int tmask = 1 << (3 - twire[e]);
                float nr[DIM], ni[DIM];
#pragma unroll
                for (int idx = 0; idx < DIM; ++idx) {
                    int src = (idx & cmask) ? (idx ^ tmask) : idx;
                    nr[idx] = vr[src]; ni[idx] = vi[src];
                }
#pragma unroll
                for (int idx = 0; idx < DIM; ++idx) { vr[idx] = nr[idx]; vi[idx] = ni[idx]; }
            }
        }
#pragma unroll
        for (int i = 0; i < DIM; ++i) { Ur[i][t] = vr[i]; Ui[i][t] = vi[i]; }
    }
    __syncthreads();
    // Mr[k][l] = sum_idx z[idx] * (Ur[idx][k]Ur[idx][l] + Ui[idx][k]Ui[idx][l])
    {
        int k = t >> 4, l = t & 15;
        float acc = 0.f;
#pragma unroll
        for (int idx = 0; idx < DIM; ++idx) {
            float z = 4.f - 2.f * (float)__popc(idx);
            acc += z * (Ur[idx][k] * Ur[idx][l] + Ui[idx][k] * Ui[idx][l]);
        }
        sMr[t] = acc;
    }
    __syncthreads();
    // compress: T[e] = (1/32) * sum_{K,L} Mr[K][L] * prod_w coeff(K_w, L_w, e_w)
    // coeff(k,l,0) = (k==l) ? 1 : 0           (constant term; per-wire 0.5 folded)
    // coeff(k,l,1) = (k==l) ? (k?-1:1) : 0    (cos t)
    // coeff(k,l,2) = (k!=l) ? 1 : 0           (sin t)
    if (t < 81) {
        int e = t;
        int e3 = e % 3, e2 = (e / 3) % 3, e1 = (e / 9) % 3, e0 = e / 27;
        int ew[4] = {e0, e1, e2, e3};
        float acc = 0.f;
        for (int K = 0; K < DIM; ++K) {
            for (int L = 0; L < DIM; ++L) {
                float prod = 1.f;
#pragma unroll
                for (int w = 0; w < 4; ++w) {
                    int kw = (K >> (3 - w)) & 1, lw = (L >> (3 - w)) & 1;
                    float cf;
                    if (ew[w] == 0)      cf = (kw == lw) ? 1.f : 0.f;
                    else if (ew[w] == 1) cf = (kw == lw) ? (kw ? -1.f : 1.f) : 0.f;
                    else                 cf = (kw != lw) ? 1.f : 0.f;
                    prod *= cf;
                }
                acc += sMr[K * 16 + L] * prod;
            }
        }
        T_out[((e0 * 3 + e1) * 3 + e2) * 4 + e3] = acc * (1.f / 32.f);
    }
    if (t < 27) T_out[t * 4 + 3] = 0.f;  // pad
}

// ---------------------------------------------------------------------------
// Kernel 2: Tq = tanh(tanh(x@Wq+bq)), Tk = tanh(tanh(x@Wk+bk)), v = x@Wv+bv.
// (store tanh of q/k so per-pair tanh(q+k) = (Tq+Tk)/(1+Tq*Tk))
// ---------------------------------------------------------------------------
__global__ __launch_bounds__(256) void k_qkv(
    const float* __restrict__ x,
    const float* __restrict__ Wq, const float* __restrict__ bq,
    const float* __restrict__ Wk, const float* __restrict__ bk,
    const float* __restrict__ Wv, const float* __restrict__ bv,
    float* __restrict__ tq, float* __restrict__ tk, float* __restrict__ v) {
    int row = blockIdx.x * 4 + (threadIdx.x >> 6);
    int lane = threadIdx.x & 63;
    const float* xr = x + (size_t)row * EE;
    float aq[4] = {0, 0, 0, 0}, ak[4] = {0, 0, 0, 0}, av[4] = {0, 0, 0, 0};
    for (int e = lane; e < EE; e += 64) {
        float xv = xr[e];
        float4 wq = *(const float4*)(Wq + e * 4);
        float4 wk = *(const float4*)(Wk + e * 4);
        float4 wv = *(const float4*)(Wv + e * 4);
        aq[0] += xv * wq.x; aq[1] += xv * wq.y; aq[2] += xv * wq.z; aq[3] += xv * wq.w;
        ak[0] += xv * wk.x; ak[1] += xv * wk.y; ak[2] += xv * wk.z; ak[3] += xv * wk.w;
        av[0] += xv * wv.x; av[1] += xv * wv.y; av[2] += xv * wv.z; av[3] += xv * wv.w;
    }
#pragma unroll
    for (int off = 32; off > 0; off >>= 1) {
#pragma unroll
        for (int c = 0; c < 4; ++c) {
            aq[c] += __shfl_down(aq[c], off, 64);
            ak[c] += __shfl_down(ak[c], off, 64);
            av[c] += __shfl_down(av[c], off, 64);
        }
    }
    if (lane == 0) {
#pragma unroll
        for (int c = 0; c < 4; ++c) {
            tq[row * 4 + c] = tanhf(tanhf(aq[c] + bq[c]));
            tk[row * 4 + c] = tanhf(tanhf(ak[c] + bk[c]));
            v[row * 4 + c] = av[c] + bv[c];
        }
    }
}

// ---------------------------------------------------------------------------
// Kernel 3: one block (256 threads) per query row; each thread handles j and
// j+256. Scores via 81-coeff trilinear form, softmax, attn write, attended.
// ---------------------------------------------------------------------------
__global__ __launch_bounds__(256) void k_attn(
    const float* __restrict__ tq, const float* __restrict__ tk,
    const float* __restrict__ v, const float* __restrict__ Tg,
    float* __restrict__ attn_out, float* __restrict__ attended) {
    int row = blockIdx.x;        // b*S + i
    int b = row >> 9;
    int tid = threadIdx.x;
    int wid = tid >> 6, lane = tid & 63;
    int j0 = tid, j1 = tid + 256;

    __shared__ float4 sT[27];
    __shared__ float rmax[4], rsum[4], rv[4][4];

    if (tid < 27) sT[tid] = ((const float4*)Tg)[tid];
    __syncthreads();

    const float4 q4 = *(const float4*)(tq + row * 4);  // wave-uniform
    const float4 ka = *(const float4*)(tk + (size_t)(b * SS + j0) * 4);
    const float4 kb = *(const float4*)(tk + (size_t)(b * SS + j1) * 4);

    // angles t_w = tanh(q_w + k_w) via addition identity
    float t0a = (q4.x + ka.x) / fmaf(q4.x, ka.x, 1.f);
    float t1a = (q4.y + ka.y) / fmaf(q4.y, ka.y, 1.f);
    float t2a = (q4.z + ka.z) / fmaf(q4.z, ka.z, 1.f);
    float t3a = (q4.w + ka.w) / fmaf(q4.w, ka.w, 1.f);
    float t0b = (q4.x + kb.x) / fmaf(q4.x, kb.x, 1.f);
    float t1b = (q4.y + kb.y) / fmaf(q4.y, kb.y, 1.f);
    float t2b = (q4.z + kb.z) / fmaf(q4.z, kb.z, 1.f);
    float t3b = (q4.w + kb.w) / fmaf(q4.w, kb.w, 1.f);

    float c0a = __cosf(t0a), s0a = __sinf(t0a);
    float c1a = __cosf(t1a), s1a = __sinf(t1a);
    float c2a = __cosf(t2a), s2a = __sinf(t2a);
    float c3a = __cosf(t3a), s3a = __sinf(t3a);
    float c0b = __cosf(t0b), s0b = __sinf(t0b);
    float c1b = __cosf(t1b), s1b = __sinf(t1b);
    float c2b = __cosf(t2b), s2b = __sinf(t2b);
    float c3b = __cosf(t3b), s3b = __sinf(t3b);

    float u0a[3] = {1.f, c0a, s0a}, u1a[3] = {1.f, c1a, s1a}, u2a[3] = {1.f, c2a, s2a};
    float u0b[3] = {1.f, c0b, s0b}, u1b[3] = {1.f, c1b, s1b}, u2b[3] = {1.f, c2b, s2b};

    float sc_a = 0.f, sc_b = 0.f;
#pragma unroll
    for (int e0 = 0; e0 < 3; ++e0) {
        float a1a = 0.f, a1b = 0.f;
#pragma unroll
        for (int e1 = 0; e1 < 3; ++e1) {
            float a2a = 0.f, a2b = 0.f;
#pragma unroll
            for (int e2 = 0; e2 < 3; ++e2) {
                float4 Tv = sT[(e0 * 3 + e1) * 3 + e2];
                float ia = fmaf(s3a, Tv.z, fmaf(c3a, Tv.y, Tv.x));
                float ib = fmaf(s3b, Tv.z, fmaf(c3b, Tv.y, Tv.x));
                a2a = fmaf(u2a[e2], ia, a2a);
                a2b = fmaf(u2b[e2], ib, a2b);
            }
            a1a = fmaf(u1a[e1], a2a, a1a);
            a1b = fmaf(u1b[e1], a2b, a1b);
        }
        sc_a = fmaf(u0a[e0], a1a, sc_a);
        sc_b = fmaf(u0b[e0], a1b, sc_b);
    }
    // (1/sqrt(4) already folded into T)

    // block softmax over 512 j's
    float m = fmaxf(sc_a, sc_b);
#pragma unroll
    for (int off = 32; off > 0; off >>= 1) m = fmaxf(m, __shfl_xor(m, off, 64));
    if (lane == 0) rmax[wid] = m;
    __syncthreads();
    float bm = fmaxf(fmaxf(rmax[0], rmax[1]), fmaxf(rmax[2], rmax[3]));

    float ex_a = __expf(sc_a - bm);
    float ex_b = __expf(sc_b - bm);
    float sum = ex_a + ex_b;
#pragma unroll
    for (int off = 32; off > 0; off >>= 1) sum += __shfl_xor(sum, off, 64);
    if (lane == 0) rsum[wid] = sum;
    __syncthreads();
    float bs = rsum[0] + rsum[1] + rsum[2] + rsum[3];
    float inv = 1.f / bs;
    float wa = ex_a * inv, wb = ex_b * inv;

    attn_out[(size_t)row * SS + j0] = wa;
    attn_out[(size_t)row * SS + j1] = wb;

    // attended[row, :] = sum_j w_j * v[b,j,:]
    const float4 va = *(const float4*)(v + (size_t)(b * SS + j0) * 4);
    const float4 vb = *(const float4*)(v + (size_t)(b * SS + j1) * 4);
    float p[4];
    p[0] = wa * va.x + wb * vb.x;
    p[1] = wa * va.y + wb * vb.y;
    p[2] = wa * va.z + wb * vb.z;
    p[3] = wa * va.w + wb * vb.w;
#pragma unroll
    for (int w = 0; w < 4; ++w) {
#pragma unroll
        for (int off = 32; off > 0; off >>= 1) p[w] += __shfl_xor(p[w], off, 64);
        if (lane == 0) rv[wid][w] = p[w];
    }
    __syncthreads();
    if (tid < 4) {
        attended[row * 4 + tid] = rv[0][tid] + rv[1][tid] + rv[2][tid] + rv[3][tid];
    }
}

// ---------------------------------------------------------------------------
// Kernel 4: out[row, e] = sum_w attended[row,w] * Wout[w,e] + bout[e]
// ---------------------------------------------------------------------------
__global__ __launch_bounds__(256) void k_out(
    const float* __restrict__ attended, const float* __restrict__ Wout,
    const float* __restrict__ bout, float* __restrict__ out) {
    int tid = blockIdx.x * blockDim.x + threadIdx.x;
    int row = tid >> 7;
    int e4 = (tid & 127) * 4;
    float a0 = attended[row * 4 + 0];
    float a1 = attended[row * 4 + 1];
    float a2 = attended[row * 4 + 2];
    float a3 = attended[row * 4 + 3];
    float4 w0 = *(const float4*)(Wout + 0 * EE + e4);
    float4 w1 = *(const float4*)(Wout + 1 * EE + e4);
    float4 w2 = *(const float4*)(Wout + 2 * EE + e4);
    float4 w3 = *(const float4*)(Wout + 3 * EE + e4);
    float4 bb = *(const float4*)(bout + e4);
    float4 o;
    o.x = a0 * w0.x + a1 * w1.x + a2 * w2.x + a3 * w3.x + bb.x;
    o.y = a0 * w0.y + a1 * w1.y + a2 * w2.y + a3 * w3.y + bb.y;
    o.z = a0 * w0.z + a1 * w1.z + a2 * w2.z + a3 * w3.z + bb.z;
    o.w = a0 * w0.w + a1 * w1.w + a2 * w2.w + a3 * w3.w + bb.w;
    *(float4*)(out + (size_t)row * EE + e4) = o;
}

extern "C" void kernel_launch(void* const* d_in, const int* in_sizes, int n_in,
                              void* d_out, int out_size, void* d_ws, size_t ws_size,
                              hipStream_t stream) {
    const float* x    = (const float*)d_in[0];
    const float* Wq   = (const float*)d_in[1];
    const float* bq   = (const float*)d_in[2];
    const float* Wk   = (const float*)d_in[3];
    const float* bk   = (const float*)d_in[4];
    const float* Wv   = (const float*)d_in[5];
    const float* bv   = (const float*)d_in[6];
    const float* qw   = (const float*)d_in[7];
    const float* Wout = (const float*)d_in[8];
    const float* bout = (const float*)d_in[9];

    float* out  = (float*)d_out;                 // [B,S,E]
    float* attn = out + (size_t)ROWS * EE;       // [B,S,S]

    float* ws  = (float*)d_ws;
    float* T   = ws;                  // 108 floats (pad to 128)
    float* tq  = ws + 128;            // 8192
    float* tk  = tq + ROWS * 4;       // 8192
    float* v   = tk + ROWS * 4;       // 8192
    float* att = v + ROWS * 4;        // 8192

    k_circuit<<<1, 256, 0, stream>>>(qw, T);
    k_qkv<<<ROWS / 4, 256, 0, stream>>>(x, Wq, bq, Wk, bk, Wv, bv, tq, tk, v);
    k_attn<<<ROWS, 256, 0, stream>>>(tq, tk, v, T, attn, att);
    k_out<<<(ROWS * 128) / 256, 256, 0, stream>>>(att, Wout, bout, out);
}

// Round 3
// 89.936 us; speedup vs baseline: 1.7537x; 1.7537x over previous
//
#include <hip/hip_runtime.h>
#include <math.h>

#define NQ 4
#define DIM 16
#define BB 4
#define SS 512
#define EE 512
#define ROWS (BB * SS)   // 2048

// ---------------------------------------------------------------------------
// Kernel 1 (fused): block 0 = circuit -> 81 trig-poly coefficients T;
// blocks 1..512 = qkv projections (4 rows per block, one wave per row).
//
// Circuit math: score/sqrt(4) = sum_e T[e] * prod_w basis_{e_w}(t_w),
// basis = {1, cos t, sin t}.  T comes from the fixed 16x16 unitary U:
//   Mr[k][l] = sum_idx z[idx] (Ur[idx][k]Ur[idx][l] + Ui[idx][k]Ui[idx][l])
//   T[e] = (1/32) sum_K (-1)^popc(K & sm_e) * Mr[K][K ^ xm_e]
// where xm_e marks wires with e_w==2 (sin) and sm_e wires with e_w==1 (cos).
// ---------------------------------------------------------------------------
__global__ __launch_bounds__(256) void k_prep(
    const float* __restrict__ x,
    const float* __restrict__ Wq, const float* __restrict__ bq,
    const float* __restrict__ Wk, const float* __restrict__ bk,
    const float* __restrict__ Wv, const float* __restrict__ bv,
    const float* __restrict__ qw,
    float* __restrict__ tq, float* __restrict__ tk, float* __restrict__ v,
    float* __restrict__ T_out) {
    if (blockIdx.x == 0) {
        // ---------------- circuit path (one block, ~2us) ----------------
        __shared__ float sG[8][8];          // per-gate complex 2x2
        __shared__ float Ur[DIM][DIM];      // [idx][col]
        __shared__ float Ui[DIM][DIM];
        __shared__ float sMr[256];
        int t = threadIdx.x;
        if (t < 8) {   // one Rot gate per thread (layer = t>>2, wire = t&3)
            float a = qw[t * 3 + 0] * 0.5f;
            float b = qw[t * 3 + 1] * 0.5f;
            float c = qw[t * 3 + 2] * 0.5f;
            float sa = __sinf(a), ca = __cosf(a);
            float sb = __sinf(b), cb = __cosf(b);
            float sc = __sinf(c), cc = __cosf(c);
            float m00r = cb * ca, m00i = sb * sa;
            float m01r = -sb * ca, m01i = -cb * sa;
            float m10r = sb * ca, m10i = -cb * sa;
            float m11r = cb * ca, m11i = -sb * sa;
            sG[t][0] = cc * m00r + sc * m00i;  // g00r
            sG[t][1] = cc * m00i - sc * m00r;  // g00i
            sG[t][2] = cc * m01r + sc * m01i;  // g01r
            sG[t][3] = cc * m01i - sc * m01r;  // g01i
            sG[t][4] = cc * m10r - sc * m10i;  // g10r
            sG[t][5] = cc * m10i + sc * m10r;  // g10i
            sG[t][6] = cc * m11r - sc * m11i;  // g11r
            sG[t][7] = cc * m11i + sc * m11r;  // g11i
        }
        __syncthreads();
        if (t < DIM) {   // simulate basis column t
            float vr[DIM], vi[DIM];
#pragma unroll
            for (int i = 0; i < DIM; ++i) { vr[i] = (i == t) ? 1.f : 0.f; vi[i] = 0.f; }
#pragma unroll
            for (int gi = 0; gi < 8; ++gi) {
                int w = gi & 3;
                float g00r = sG[gi][0], g00i = sG[gi][1];
                float g01r = sG[gi][2], g01i = sG[gi][3];
                float g10r = sG[gi][4], g10i = sG[gi][5];
                float g11r = sG[gi][6], g11i = sG[gi][7];
                int mask = 1 << (3 - w);
#pragma unroll
                for (int idx = 0; idx < DIM; ++idx) {
                    if (idx & mask) continue;
                    int i1 = idx | mask;
                    float r0 = vr[idx], i0 = vi[idx], r1 = vr[i1], i1v = vi[i1];
                    vr[idx] = g00r * r0 - g00i * i0 + g01r * r1 - g01i * i1v;
                    vi[idx] = g00r * i0 + g00i * r0 + g01r * i1v + g01i * r1;
                    vr[i1]  = g10r * r0 - g10i * i0 + g11r * r1 - g11i * i1v;
                    vi[i1]  = g10r * i0 + g10i * r0 + g11r * i1v + g11i * r1;
                }
                if (w == 3) {  // end of layer: CNOT chain (0,1),(1,2),(2,3),(3,0)
                    const int cwire[4] = {0, 1, 2, 3};
                    const int twire[4] = {1, 2, 3, 0};
#pragma unroll
                    for (int e = 0; e < 4; ++e) {
                        int cmask = 1 << (3 - cwire[e]);
                        int tmask = 1 << (3 - twire[e]);
                        float nr[DIM], ni[DIM];
#pragma unroll
                        for (int idx = 0; idx < DIM; ++idx) {
                            int src = (idx & cmask) ? (idx ^ tmask) : idx;
                            nr[idx] = vr[src]; ni[idx] = vi[src];
                        }
#pragma unroll
                        for (int idx = 0; idx < DIM; ++idx) { vr[idx] = nr[idx]; vi[idx] = ni[idx]; }
                    }
                }
            }
#pragma unroll
            for (int i = 0; i < DIM; ++i) { Ur[i][t] = vr[i]; Ui[i][t] = vi[i]; }
        }
        __syncthreads();
        {   // Mr entry per thread
            int k = t >> 4, l = t & 15;
            float acc = 0.f;
#pragma unroll
            for (int idx = 0; idx < DIM; ++idx) {
                float z = 4.f - 2.f * (float)__popc(idx);
                acc += z * (Ur[idx][k] * Ur[idx][l] + Ui[idx][k] * Ui[idx][l]);
            }
            sMr[t] = acc;
        }
        __syncthreads();
        if (t < 81) {   // closed-form compression: 16 terms per coefficient
            int e3 = t % 3, e2 = (t / 3) % 3, e1 = (t / 9) % 3, e0 = t / 27;
            int xm = ((e0 == 2) << 3) | ((e1 == 2) << 2) | ((e2 == 2) << 1) | (int)(e3 == 2);
            int sm = ((e0 == 1) << 3) | ((e1 == 1) << 2) | ((e2 == 1) << 1) | (int)(e3 == 1);
            float acc = 0.f;
#pragma unroll
            for (int K = 0; K < DIM; ++K) {
                float s = (__popc(K & sm) & 1) ? -1.f : 1.f;
                acc += s * sMr[K * 16 + (K ^ xm)];
            }
            T_out[((e0 * 3 + e1) * 3 + e2) * 4 + e3] = acc * (1.f / 32.f);
        }
        if (t < 27) T_out[t * 4 + 3] = 0.f;  // pad for float4 loads
    } else {
        // ---------------- qkv path (512 blocks, one wave per row) ----------------
        int row = (blockIdx.x - 1) * 4 + (threadIdx.x >> 6);
        int lane = threadIdx.x & 63;
        const float* xr = x + (size_t)row * EE;
        float aq[4] = {0, 0, 0, 0}, ak[4] = {0, 0, 0, 0}, av[4] = {0, 0, 0, 0};
        for (int e = lane; e < EE; e += 64) {
            float xv = xr[e];
            float4 wq = *(const float4*)(Wq + e * 4);
            float4 wk = *(const float4*)(Wk + e * 4);
            float4 wv = *(const float4*)(Wv + e * 4);
            aq[0] += xv * wq.x; aq[1] += xv * wq.y; aq[2] += xv * wq.z; aq[3] += xv * wq.w;
            ak[0] += xv * wk.x; ak[1] += xv * wk.y; ak[2] += xv * wk.z; ak[3] += xv * wk.w;
            av[0] += xv * wv.x; av[1] += xv * wv.y; av[2] += xv * wv.z; av[3] += xv * wv.w;
        }
#pragma unroll
        for (int off = 32; off > 0; off >>= 1) {
#pragma unroll
            for (int c = 0; c < 4; ++c) {
                aq[c] += __shfl_down(aq[c], off, 64);
                ak[c] += __shfl_down(ak[c], off, 64);
                av[c] += __shfl_down(av[c], off, 64);
            }
        }
        if (lane == 0) {
#pragma unroll
            for (int c = 0; c < 4; ++c) {
                tq[row * 4 + c] = tanhf(tanhf(aq[c] + bq[c]));
                tk[row * 4 + c] = tanhf(tanhf(ak[c] + bk[c]));
                v[row * 4 + c] = av[c] + bv[c];
            }
        }
    }
}

// ---------------------------------------------------------------------------
// Kernel 2: one block (256 threads) per query row; each thread handles j and
// j+256. Scores via 81-coeff trilinear form, softmax, attn write, attended
// reduction, and fused output projection (out = attended @ Wout + bout).
// ---------------------------------------------------------------------------
__global__ __launch_bounds__(256) void k_attn(
    const float* __restrict__ tq, const float* __restrict__ tk,
    const float* __restrict__ v, const float* __restrict__ Tg,
    const float* __restrict__ Wout, const float* __restrict__ bout,
    float* __restrict__ attn_out, float* __restrict__ out) {
    int row = blockIdx.x;        // b*S + i
    int b = row >> 9;
    int tid = threadIdx.x;
    int wid = tid >> 6, lane = tid & 63;
    int j0 = tid, j1 = tid + 256;

    __shared__ float4 sT[27];
    __shared__ float rmax[4], rsum[4], rv[4][4];

    if (tid < 27) sT[tid] = ((const float4*)Tg)[tid];
    __syncthreads();

    const float4 q4 = *(const float4*)(tq + row * 4);  // wave-uniform
    const float4 ka = *(const float4*)(tk + (size_t)(b * SS + j0) * 4);
    const float4 kb = *(const float4*)(tk + (size_t)(b * SS + j1) * 4);

    // t_w = tanh(q_w + k_w) via addition identity on pre-tanh'd values
    float t0a = (q4.x + ka.x) / fmaf(q4.x, ka.x, 1.f);
    float t1a = (q4.y + ka.y) / fmaf(q4.y, ka.y, 1.f);
    float t2a = (q4.z + ka.z) / fmaf(q4.z, ka.z, 1.f);
    float t3a = (q4.w + ka.w) / fmaf(q4.w, ka.w, 1.f);
    float t0b = (q4.x + kb.x) / fmaf(q4.x, kb.x, 1.f);
    float t1b = (q4.y + kb.y) / fmaf(q4.y, kb.y, 1.f);
    float t2b = (q4.z + kb.z) / fmaf(q4.z, kb.z, 1.f);
    float t3b = (q4.w + kb.w) / fmaf(q4.w, kb.w, 1.f);

    float c0a = __cosf(t0a), s0a = __sinf(t0a);
    float c1a = __cosf(t1a), s1a = __sinf(t1a);
    float c2a = __cosf(t2a), s2a = __sinf(t2a);
    float c3a = __cosf(t3a), s3a = __sinf(t3a);
    float c0b = __cosf(t0b), s0b = __sinf(t0b);
    float c1b = __cosf(t1b), s1b = __sinf(t1b);
    float c2b = __cosf(t2b), s2b = __sinf(t2b);
    float c3b = __cosf(t3b), s3b = __sinf(t3b);

    float u0a[3] = {1.f, c0a, s0a}, u1a[3] = {1.f, c1a, s1a}, u2a[3] = {1.f, c2a, s2a};
    float u0b[3] = {1.f, c0b, s0b}, u1b[3] = {1.f, c1b, s1b}, u2b[3] = {1.f, c2b, s2b};

    float sc_a = 0.f, sc_b = 0.f;
#pragma unroll
    for (int e0 = 0; e0 < 3; ++e0) {
        float a1a = 0.f, a1b = 0.f;
#pragma unroll
        for (int e1 = 0; e1 < 3; ++e1) {
            float a2a = 0.f, a2b = 0.f;
#pragma unroll
            for (int e2 = 0; e2 < 3; ++e2) {
                float4 Tv = sT[(e0 * 3 + e1) * 3 + e2];
                float ia = fmaf(s3a, Tv.z, fmaf(c3a, Tv.y, Tv.x));
                float ib = fmaf(s3b, Tv.z, fmaf(c3b, Tv.y, Tv.x));
                a2a = fmaf(u2a[e2], ia, a2a);
                a2b = fmaf(u2b[e2], ib, a2b);
            }
            a1a = fmaf(u1a[e1], a2a, a1a);
            a1b = fmaf(u1b[e1], a2b, a1b);
        }
        sc_a = fmaf(u0a[e0], a1a, sc_a);
        sc_b = fmaf(u0b[e0], a1b, sc_b);
    }

    // block softmax over 512 j's
    float m = fmaxf(sc_a, sc_b);
#pragma unroll
    for (int off = 32; off > 0; off >>= 1) m = fmaxf(m, __shfl_xor(m, off, 64));
    if (lane == 0) rmax[wid] = m;
    __syncthreads();
    float bm = fmaxf(fmaxf(rmax[0], rmax[1]), fmaxf(rmax[2], rmax[3]));

    float ex_a = __expf(sc_a - bm);
    float ex_b = __expf(sc_b - bm);
    float sum = ex_a + ex_b;
#pragma unroll
    for (int off = 32; off > 0; off >>= 1) sum += __shfl_xor(sum, off, 64);
    if (lane == 0) rsum[wid] = sum;
    __syncthreads();
    float bs = rsum[0] + rsum[1] + rsum[2] + rsum[3];
    float inv = 1.f / bs;
    float wa = ex_a * inv, wb = ex_b * inv;

    attn_out[(size_t)row * SS + j0] = wa;
    attn_out[(size_t)row * SS + j1] = wb;

    // attended[row, :] = sum_j w_j * v[b,j,:]
    const float4 va = *(const float4*)(v + (size_t)(b * SS + j0) * 4);
    const float4 vb = *(const float4*)(v + (size_t)(b * SS + j1) * 4);
    float p[4];
    p[0] = wa * va.x + wb * vb.x;
    p[1] = wa * va.y + wb * vb.y;
    p[2] = wa * va.z + wb * vb.z;
    p[3] = wa * va.w + wb * vb.w;
#pragma unroll
    for (int w = 0; w < 4; ++w) {
#pragma unroll
        for (int off = 32; off > 0; off >>= 1) p[w] += __shfl_xor(p[w], off, 64);
        if (lane == 0) rv[wid][w] = p[w];
    }
    __syncthreads();

    // fused output projection: out[row, e] = sum_w att_w * Wout[w,e] + bout[e]
    float a0 = rv[0][0] + rv[1][0] + rv[2][0] + rv[3][0];
    float a1 = rv[0][1] + rv[1][1] + rv[2][1] + rv[3][1];
    float a2 = rv[0][2] + rv[1][2] + rv[2][2] + rv[3][2];
    float a3 = rv[0][3] + rv[1][3] + rv[2][3] + rv[3][3];
    int e = tid * 2;
    float2 w0 = *(const float2*)(Wout + 0 * EE + e);
    float2 w1 = *(const float2*)(Wout + 1 * EE + e);
    float2 w2 = *(const float2*)(Wout + 2 * EE + e);
    float2 w3 = *(const float2*)(Wout + 3 * EE + e);
    float2 bb = *(const float2*)(bout + e);
    float2 o;
    o.x = fmaf(a0, w0.x, fmaf(a1, w1.x, fmaf(a2, w2.x, fmaf(a3, w3.x, bb.x))));
    o.y = fmaf(a0, w0.y, fmaf(a1, w1.y, fmaf(a2, w2.y, fmaf(a3, w3.y, bb.y))));
    *(float2*)(out + (size_t)row * EE + e) = o;
}

extern "C" void kernel_launch(void* const* d_in, const int* in_sizes, int n_in,
                              void* d_out, int out_size, void* d_ws, size_t ws_size,
                              hipStream_t stream) {
    const float* x    = (const float*)d_in[0];
    const float* Wq   = (const float*)d_in[1];
    const float* bq   = (const float*)d_in[2];
    const float* Wk   = (const float*)d_in[3];
    const float* bk   = (const float*)d_in[4];
    const float* Wv   = (const float*)d_in[5];
    const float* bv   = (const float*)d_in[6];
    const float* qw   = (const float*)d_in[7];
    const float* Wout = (const float*)d_in[8];
    const float* bout = (const float*)d_in[9];

    float* out  = (float*)d_out;                 // [B,S,E]
    float* attn = out + (size_t)ROWS * EE;       // [B,S,S]

    float* ws  = (float*)d_ws;
    float* T   = ws;                  // 108 floats (pad to 128)
    float* tq  = ws + 128;            // 8192
    float* tk  = tq + ROWS * 4;       // 8192
    float* v   = tk + ROWS * 4;       // 8192

    k_prep<<<1 + ROWS / 4, 256, 0, stream>>>(x, Wq, bq, Wk, bk, Wv, bv, qw, tq, tk, v, T);
    k_attn<<<ROWS, 256, 0, stream>>>(tq, tk, v, T, Wout, bout, attn, out);
}

// Round 4
// 87.848 us; speedup vs baseline: 1.7954x; 1.0238x over previous
//
#include <hip/hip_runtime.h>
#include <math.h>

#define NQ 4
#define DIM 16
#define BB 4
#define SS 512
#define EE 512
#define ROWS (BB * SS)   // 2048

// ---------------------------------------------------------------------------
// Kernel 1 (fused): block 0 = circuit -> 81 trig-poly coefficients T;
// blocks 1..512 = qkv projections (4 rows per block, one wave per row).
//
// score/sqrt(4) = sum_e T[e] * prod_w basis_{e_w}(t_w), basis = {1,cos,sin};
//   Mr[k][l] = sum_idx z[idx] (Ur[idx][k]Ur[idx][l] + Ui[idx][k]Ui[idx][l])
//   T[e] = (1/32) sum_K (-1)^popc(K & sm_e) * Mr[K][K ^ xm_e]
// ---------------------------------------------------------------------------
__global__ __launch_bounds__(256) void k_prep(
    const float* __restrict__ x,
    const float* __restrict__ Wq, const float* __restrict__ bq,
    const float* __restrict__ Wk, const float* __restrict__ bk,
    const float* __restrict__ Wv, const float* __restrict__ bv,
    const float* __restrict__ qw,
    float* __restrict__ tq, float* __restrict__ tk, float* __restrict__ v,
    float* __restrict__ T_out) {
    if (blockIdx.x == 0) {
        // ---------------- circuit path (one block) ----------------
        __shared__ float sG[8][8];
        __shared__ float Ur[DIM][DIM];
        __shared__ float Ui[DIM][DIM];
        __shared__ float sMr[256];
        int t = threadIdx.x;
        if (t < 8) {   // one Rot gate per thread
            float a = qw[t * 3 + 0] * 0.5f;
            float b = qw[t * 3 + 1] * 0.5f;
            float c = qw[t * 3 + 2] * 0.5f;
            float sa = __sinf(a), ca = __cosf(a);
            float sb = __sinf(b), cb = __cosf(b);
            float sc = __sinf(c), cc = __cosf(c);
            float m00r = cb * ca, m00i = sb * sa;
            float m01r = -sb * ca, m01i = -cb * sa;
            float m10r = sb * ca, m10i = -cb * sa;
            float m11r = cb * ca, m11i = -sb * sa;
            sG[t][0] = cc * m00r + sc * m00i;
            sG[t][1] = cc * m00i - sc * m00r;
            sG[t][2] = cc * m01r + sc * m01i;
            sG[t][3] = cc * m01i - sc * m01r;
            sG[t][4] = cc * m10r - sc * m10i;
            sG[t][5] = cc * m10i + sc * m10r;
            sG[t][6] = cc * m11r - sc * m11i;
            sG[t][7] = cc * m11i + sc * m11r;
        }
        __syncthreads();
        if (t < DIM) {   // simulate basis column t
            float vr[DIM], vi[DIM];
#pragma unroll
            for (int i = 0; i < DIM; ++i) { vr[i] = (i == t) ? 1.f : 0.f; vi[i] = 0.f; }
#pragma unroll
            for (int gi = 0; gi < 8; ++gi) {
                int w = gi & 3;
                float g00r = sG[gi][0], g00i = sG[gi][1];
                float g01r = sG[gi][2], g01i = sG[gi][3];
                float g10r = sG[gi][4], g10i = sG[gi][5];
                float g11r = sG[gi][6], g11i = sG[gi][7];
                int mask = 1 << (3 - w);
#pragma unroll
                for (int idx = 0; idx < DIM; ++idx) {
                    if (idx & mask) continue;
                    int i1 = idx | mask;
                    float r0 = vr[idx], i0 = vi[idx], r1 = vr[i1], i1v = vi[i1];
                    vr[idx] = g00r * r0 - g00i * i0 + g01r * r1 - g01i * i1v;
                    vi[idx] = g00r * i0 + g00i * r0 + g01r * i1v + g01i * r1;
                    vr[i1]  = g10r * r0 - g10i * i0 + g11r * r1 - g11i * i1v;
                    vi[i1]  = g10r * i0 + g10i * r0 + g11r * i1v + g11i * r1;
                }
                if (w == 3) {  // CNOT chain (0,1),(1,2),(2,3),(3,0)
                    const int cwire[4] = {0, 1, 2, 3};
                    const int twire[4] = {1, 2, 3, 0};
#pragma unroll
                    for (int e = 0; e < 4; ++e) {
                        int cmask = 1 << (3 - cwire[e]);
                        int tmask = 1 << (3 - twire[e]);
                        float nr[DIM], ni[DIM];
#pragma unroll
                        for (int idx = 0; idx < DIM; ++idx) {
                            int src = (idx & cmask) ? (idx ^ tmask) : idx;
                            nr[idx] = vr[src]; ni[idx] = vi[src];
                        }
#pragma unroll
                        for (int idx = 0; idx < DIM; ++idx) { vr[idx] = nr[idx]; vi[idx] = ni[idx]; }
                    }
                }
            }
#pragma unroll
            for (int i = 0; i < DIM; ++i) { Ur[i][t] = vr[i]; Ui[i][t] = vi[i]; }
        }
        __syncthreads();
        {
            int k = t >> 4, l = t & 15;
            float acc = 0.f;
#pragma unroll
            for (int idx = 0; idx < DIM; ++idx) {
                float z = 4.f - 2.f * (float)__popc(idx);
                acc += z * (Ur[idx][k] * Ur[idx][l] + Ui[idx][k] * Ui[idx][l]);
            }
            sMr[t] = acc;
        }
        __syncthreads();
        if (t < 81) {
            int e3 = t % 3, e2 = (t / 3) % 3, e1 = (t / 9) % 3, e0 = t / 27;
            int xm = ((e0 == 2) << 3) | ((e1 == 2) << 2) | ((e2 == 2) << 1) | (int)(e3 == 2);
            int sm = ((e0 == 1) << 3) | ((e1 == 1) << 2) | ((e2 == 1) << 1) | (int)(e3 == 1);
            float acc = 0.f;
#pragma unroll
            for (int K = 0; K < DIM; ++K) {
                float s = (__popc(K & sm) & 1) ? -1.f : 1.f;
                acc += s * sMr[K * 16 + (K ^ xm)];
            }
            T_out[((e0 * 3 + e1) * 3 + e2) * 4 + e3] = acc * (1.f / 32.f);
        }
        if (t < 27) T_out[t * 4 + 3] = 0.f;
    } else {
        // ---------------- qkv path: one wave per row, float4 x loads ----------------
        int row = (blockIdx.x - 1) * 4 + (threadIdx.x >> 6);
        int lane = threadIdx.x & 63;
        const float4* xr4 = (const float4*)(x + (size_t)row * EE);
        float aq[4] = {0, 0, 0, 0}, ak[4] = {0, 0, 0, 0}, av[4] = {0, 0, 0, 0};
#pragma unroll
        for (int h = 0; h < 2; ++h) {
            int e4 = lane + h * 64;          // float4 index; e = e4*4
            float4 xv = xr4[e4];
            float xc[4] = {xv.x, xv.y, xv.z, xv.w};
#pragma unroll
            for (int c = 0; c < 4; ++c) {
                int e = e4 * 4 + c;
                float4 wq = *(const float4*)(Wq + e * 4);
                float4 wk = *(const float4*)(Wk + e * 4);
                float4 wv = *(const float4*)(Wv + e * 4);
                aq[0] = fmaf(xc[c], wq.x, aq[0]); aq[1] = fmaf(xc[c], wq.y, aq[1]);
                aq[2] = fmaf(xc[c], wq.z, aq[2]); aq[3] = fmaf(xc[c], wq.w, aq[3]);
                ak[0] = fmaf(xc[c], wk.x, ak[0]); ak[1] = fmaf(xc[c], wk.y, ak[1]);
                ak[2] = fmaf(xc[c], wk.z, ak[2]); ak[3] = fmaf(xc[c], wk.w, ak[3]);
                av[0] = fmaf(xc[c], wv.x, av[0]); av[1] = fmaf(xc[c], wv.y, av[1]);
                av[2] = fmaf(xc[c], wv.z, av[2]); av[3] = fmaf(xc[c], wv.w, av[3]);
            }
        }
#pragma unroll
        for (int off = 32; off > 0; off >>= 1) {
#pragma unroll
            for (int c = 0; c < 4; ++c) {
                aq[c] += __shfl_down(aq[c], off, 64);
                ak[c] += __shfl_down(ak[c], off, 64);
                av[c] += __shfl_down(av[c], off, 64);
            }
        }
        if (lane == 0) {
#pragma unroll
            for (int c = 0; c < 4; ++c) {
                tq[row * 4 + c] = tanhf(tanhf(aq[c] + bq[c]));
                tk[row * 4 + c] = tanhf(tanhf(ak[c] + bk[c]));
                v[row * 4 + c] = av[c] + bv[c];
            }
        }
    }
}

// ---------------------------------------------------------------------------
// Kernel 2: one block (256 threads) per query row; thread handles j, j+256.
// No-max softmax (|sc| <= 2 provably), single fused 5-value reduction
// {sum_ex, sum_ex*v[0..3]}, fused output projection.
// ---------------------------------------------------------------------------
__global__ __launch_bounds__(256) void k_attn(
    const float* __restrict__ tq, const float* __restrict__ tk,
    const float* __restrict__ v, const float* __restrict__ Tg,
    const float* __restrict__ Wout, const float* __restrict__ bout,
    float* __restrict__ attn_out, float* __restrict__ out) {
    int row = blockIdx.x;        // b*S + i
    int b = row >> 9;
    int tid = threadIdx.x;
    int wid = tid >> 6, lane = tid & 63;
    int j0 = tid, j1 = tid + 256;

    __shared__ float4 sT[27];
    __shared__ float red[4][5];

    if (tid < 27) sT[tid] = ((const float4*)Tg)[tid];
    __syncthreads();

    const float4 q4 = *(const float4*)(tq + row * 4);  // wave-uniform
    const float4 ka = *(const float4*)(tk + (size_t)(b * SS + j0) * 4);
    const float4 kb = *(const float4*)(tk + (size_t)(b * SS + j1) * 4);

    // t_w = tanh(q_w + k_w) via addition identity on pre-tanh'd values
    float t0a = (q4.x + ka.x) / fmaf(q4.x, ka.x, 1.f);
    float t1a = (q4.y + ka.y) / fmaf(q4.y, ka.y, 1.f);
    float t2a = (q4.z + ka.z) / fmaf(q4.z, ka.z, 1.f);
    float t3a = (q4.w + ka.w) / fmaf(q4.w, ka.w, 1.f);
    float t0b = (q4.x + kb.x) / fmaf(q4.x, kb.x, 1.f);
    float t1b = (q4.y + kb.y) / fmaf(q4.y, kb.y, 1.f);
    float t2b = (q4.z + kb.z) / fmaf(q4.z, kb.z, 1.f);
    float t3b = (q4.w + kb.w) / fmaf(q4.w, kb.w, 1.f);

    float c0a = __cosf(t0a), s0a = __sinf(t0a);
    float c1a = __cosf(t1a), s1a = __sinf(t1a);
    float c2a = __cosf(t2a), s2a = __sinf(t2a);
    float c3a = __cosf(t3a), s3a = __sinf(t3a);
    float c0b = __cosf(t0b), s0b = __sinf(t0b);
    float c1b = __cosf(t1b), s1b = __sinf(t1b);
    float c2b = __cosf(t2b), s2b = __sinf(t2b);
    float c3b = __cosf(t3b), s3b = __sinf(t3b);

    float u0a[3] = {1.f, c0a, s0a}, u1a[3] = {1.f, c1a, s1a}, u2a[3] = {1.f, c2a, s2a};
    float u0b[3] = {1.f, c0b, s0b}, u1b[3] = {1.f, c1b, s1b}, u2b[3] = {1.f, c2b, s2b};

    float sc_a = 0.f, sc_b = 0.f;
#pragma unroll
    for (int e0 = 0; e0 < 3; ++e0) {
        float a1a = 0.f, a1b = 0.f;
#pragma unroll
        for (int e1 = 0; e1 < 3; ++e1) {
            float a2a = 0.f, a2b = 0.f;
#pragma unroll
            for (int e2 = 0; e2 < 3; ++e2) {
                float4 Tv = sT[(e0 * 3 + e1) * 3 + e2];
                float ia = fmaf(s3a, Tv.z, fmaf(c3a, Tv.y, Tv.x));
                float ib = fmaf(s3b, Tv.z, fmaf(c3b, Tv.y, Tv.x));
                a2a = fmaf(u2a[e2], ia, a2a);
                a2b = fmaf(u2b[e2], ib, a2b);
            }
            a1a = fmaf(u1a[e1], a2a, a1a);
            a1b = fmaf(u1b[e1], a2b, a1b);
        }
        sc_a = fmaf(u0a[e0], a1a, sc_a);
        sc_b = fmaf(u0b[e0], a1b, sc_b);
    }

    // |sc| <= 2 (||amp||=1, ||M||_2 <= 4, /2 scale) -> no max subtraction needed
    float ex_a = __expf(sc_a);
    float ex_b = __expf(sc_b);

    const float4 va = *(const float4*)(v + (size_t)(b * SS + j0) * 4);
    const float4 vb = *(const float4*)(v + (size_t)(b * SS + j1) * 4);
    float vals[5];
    vals[0] = ex_a + ex_b;
    vals[1] = fmaf(ex_a, va.x, ex_b * vb.x);
    vals[2] = fmaf(ex_a, va.y, ex_b * vb.y);
    vals[3] = fmaf(ex_a, va.z, ex_b * vb.z);
    vals[4] = fmaf(ex_a, va.w, ex_b * vb.w);
#pragma unroll
    for (int off = 32; off > 0; off >>= 1) {
#pragma unroll
        for (int c = 0; c < 5; ++c) vals[c] += __shfl_xor(vals[c], off, 64);
    }
    if (lane == 0) {
#pragma unroll
        for (int c = 0; c < 5; ++c) red[wid][c] = vals[c];
    }
    __syncthreads();

    float tot = red[0][0] + red[1][0] + red[2][0] + red[3][0];
    float inv = 1.f / tot;

    attn_out[(size_t)row * SS + j0] = ex_a * inv;
    attn_out[(size_t)row * SS + j1] = ex_b * inv;

    float a0 = (red[0][1] + red[1][1] + red[2][1] + red[3][1]) * inv;
    float a1 = (red[0][2] + red[1][2] + red[2][2] + red[3][2]) * inv;
    float a2 = (red[0][3] + red[1][3] + red[2][3] + red[3][3]) * inv;
    float a3 = (red[0][4] + red[1][4] + red[2][4] + red[3][4]) * inv;

    // fused output projection: out[row, e] = sum_w a_w * Wout[w,e] + bout[e]
    int e = tid * 2;
    float2 w0 = *(const float2*)(Wout + 0 * EE + e);
    float2 w1 = *(const float2*)(Wout + 1 * EE + e);
    float2 w2 = *(const float2*)(Wout + 2 * EE + e);
    float2 w3 = *(const float2*)(Wout + 3 * EE + e);
    float2 bb = *(const float2*)(bout + e);
    float2 o;
    o.x = fmaf(a0, w0.x, fmaf(a1, w1.x, fmaf(a2, w2.x, fmaf(a3, w3.x, bb.x))));
    o.y = fmaf(a0, w0.y, fmaf(a1, w1.y, fmaf(a2, w2.y, fmaf(a3, w3.y, bb.y))));
    *(float2*)(out + (size_t)row * EE + e) = o;
}

extern "C" void kernel_launch(void* const* d_in, const int* in_sizes, int n_in,
                              void* d_out, int out_size, void* d_ws, size_t ws_size,
                              hipStream_t stream) {
    const float* x    = (const float*)d_in[0];
    const float* Wq   = (const float*)d_in[1];
    const float* bq   = (const float*)d_in[2];
    const float* Wk   = (const float*)d_in[3];
    const float* bk   = (const float*)d_in[4];
    const float* Wv   = (const float*)d_in[5];
    const float* bv   = (const float*)d_in[6];
    const float* qw   = (const float*)d_in[7];
    const float* Wout = (const float*)d_in[8];
    const float* bout = (const float*)d_in[9];

    float* out  = (float*)d_out;                 // [B,S,E]
    float* attn = out + (size_t)ROWS * EE;       // [B,S,S]

    float* ws  = (float*)d_ws;
    float* T   = ws;                  // 108 floats (pad to 128)
    float* tq  = ws + 128;            // 8192
    float* tk  = tq + ROWS * 4;       // 8192
    float* v   = tk + ROWS * 4;       // 8192

    k_prep<<<1 + ROWS / 4, 256, 0, stream>>>(x, Wq, bq, Wk, bk, Wv, bv, qw, tq, tk, v, T);
    k_attn<<<ROWS, 256, 0, stream>>>(tq, tk, v, T, Wout, bout, attn, out);
}